// Round 3
// baseline (27061.072 us; speedup 1.0000x reference)
//
#include <hip/hip_runtime.h>
#include <math.h>

namespace {

constexpr int T = 512;
constexpr int B = 64;
constexpr int D = 1024;
constexpr int H = 1024;
constexpr int G4 = 4 * H;  // 4096

// ---------------------------------------------------------------------------
// Phase 1: G[t*B+b][n] = sum_k x[t][b][k] * W_ih[n][k] + b_ih[n] + b_hh[n]
// Plain fp32 NT-SGEMM, 64x64 tile, BK=32, 256 threads, 4x4 per thread.
// ---------------------------------------------------------------------------
__global__ __launch_bounds__(256)
void gemm_xWih_kernel(const float* __restrict__ A,   // [M=T*B][D]
                      const float* __restrict__ W,   // [4096][D]
                      const float* __restrict__ b_ih,
                      const float* __restrict__ b_hh,
                      float* __restrict__ C)         // [M][4096]
{
    __shared__ float As[32][68];
    __shared__ float Ws[32][68];
    const int tid = threadIdx.x;
    const int m0 = blockIdx.y * 64;
    const int n0 = blockIdx.x * 64;
    const int tx = tid & 15;   // n dir
    const int ty = tid >> 4;   // m dir
    float acc[4][4] = {};

#pragma unroll 1
    for (int k0 = 0; k0 < D; k0 += 32) {
#pragma unroll
        for (int l = 0; l < 2; ++l) {
            int idx = l * 256 + tid;
            int r = idx >> 3;
            int kk = (idx & 7) << 2;
            float4 va = *(const float4*)(A + (size_t)(m0 + r) * D + k0 + kk);
            As[kk + 0][r] = va.x; As[kk + 1][r] = va.y;
            As[kk + 2][r] = va.z; As[kk + 3][r] = va.w;
            float4 vw = *(const float4*)(W + (size_t)(n0 + r) * D + k0 + kk);
            Ws[kk + 0][r] = vw.x; Ws[kk + 1][r] = vw.y;
            Ws[kk + 2][r] = vw.z; Ws[kk + 3][r] = vw.w;
        }
        __syncthreads();
#pragma unroll
        for (int k = 0; k < 32; ++k) {
            float4 a = *(const float4*)&As[k][ty << 2];
            float4 b = *(const float4*)&Ws[k][tx << 2];
            acc[0][0] = fmaf(a.x, b.x, acc[0][0]);
            acc[0][1] = fmaf(a.x, b.y, acc[0][1]);
            acc[0][2] = fmaf(a.x, b.z, acc[0][2]);
            acc[0][3] = fmaf(a.x, b.w, acc[0][3]);
            acc[1][0] = fmaf(a.y, b.x, acc[1][0]);
            acc[1][1] = fmaf(a.y, b.y, acc[1][1]);
            acc[1][2] = fmaf(a.y, b.z, acc[1][2]);
            acc[1][3] = fmaf(a.y, b.w, acc[1][3]);
            acc[2][0] = fmaf(a.z, b.x, acc[2][0]);
            acc[2][1] = fmaf(a.z, b.y, acc[2][1]);
            acc[2][2] = fmaf(a.z, b.z, acc[2][2]);
            acc[2][3] = fmaf(a.z, b.w, acc[2][3]);
            acc[3][0] = fmaf(a.w, b.x, acc[3][0]);
            acc[3][1] = fmaf(a.w, b.y, acc[3][1]);
            acc[3][2] = fmaf(a.w, b.z, acc[3][2]);
            acc[3][3] = fmaf(a.w, b.w, acc[3][3]);
        }
        __syncthreads();
    }
#pragma unroll
    for (int i = 0; i < 4; ++i) {
        int m = m0 + (ty << 2) + i;
        int n = n0 + (tx << 2);
        float4 o;
        o.x = acc[i][0] + b_ih[n + 0] + b_hh[n + 0];
        o.y = acc[i][1] + b_ih[n + 1] + b_hh[n + 1];
        o.z = acc[i][2] + b_ih[n + 2] + b_hh[n + 2];
        o.w = acc[i][3] + b_ih[n + 3] + b_hh[n + 3];
        *(float4*)(C + (size_t)m * G4 + n) = o;
    }
}

__device__ __forceinline__ float sigmoidf_(float v) {
    return 1.0f / (1.0f + expf(-v));
}

// ---------------------------------------------------------------------------
// Phase 2: one step of the reverse TLSTM.
// Grid = 256 WGs x 256 threads. WG owns 4 output columns j0..j0+3.
// Thread (bq,jl,rep) accumulates 4 batches (b = bq+16i) x 1 column x 5 rows
// (i,f,g,o via W_hh, d via W_d) over K-slice rep; LDS reduction across reps.
// FUSED variant (no precomputed G): K extends to 2048 with [h ; x_t] vs
// [W_hh ; W_ih]; the d (W_d) accumulation only runs on the first 1024.
// ---------------------------------------------------------------------------
template <bool FUSED>
__global__ __launch_bounds__(256)
void tlstm_step(const float* __restrict__ h_in,   // [B][H]
                const float* __restrict__ c_in,   // [B][H]
                const float* __restrict__ gvec,   // !FUSED: G+t*B*4096, FUSED: x_t
                const float* __restrict__ W_hh,   // [4096][H]
                const float* __restrict__ W_ih,   // [4096][D]
                const float* __restrict__ W_d,    // [H][H]
                const float* __restrict__ b_ih,
                const float* __restrict__ b_hh,
                const float* __restrict__ b_d,
                const float* __restrict__ dts,    // [B]
                float* __restrict__ h_out,        // outs + t*B*H
                float* __restrict__ c_out)        // [B][H]
{
    __shared__ float hs[64][68];
    __shared__ float cs[64][68];
    __shared__ float ws[20][68];
    __shared__ float red[256][21];

    const int tid = threadIdx.x;
    const int j0 = blockIdx.x * 4;
    const int bq = tid & 15;
    const int jl = (tid >> 4) & 3;
    const int rep = tid >> 6;
    const int j = j0 + jl;

    float acc[4][5] = {};  // [i: b = bq+16*i][gate: i,f,g,o,d]

    const int KTOT = FUSED ? 2048 : 1024;
#pragma unroll 1
    for (int k0 = 0; k0 < KTOT; k0 += 64) {
        const bool first_half = (!FUSED) || (k0 < 1024);
        const int kc = first_half ? k0 : (k0 - 1024);
        const float* hsrc = first_half ? h_in : gvec;  // gvec == x_t when FUSED

        // stage h (or x_t) tile: 64 rows x 64 cols
#pragma unroll
        for (int l = 0; l < 4; ++l) {
            int idx = l * 256 + tid;
            int r = idx >> 4;
            int c4 = (idx & 15) << 2;
            *(float4*)&hs[r][c4] =
                *(const float4*)(hsrc + (size_t)r * 1024 + kc + c4);
        }
        if (first_half) {
#pragma unroll
            for (int l = 0; l < 4; ++l) {
                int idx = l * 256 + tid;
                int r = idx >> 4;
                int c4 = (idx & 15) << 2;
                *(float4*)&cs[r][c4] =
                    *(const float4*)(c_in + (size_t)r * 1024 + kc + c4);
            }
        }
        // stage 20 weight rows x 64 cols (i,f,g,o for 4 cols + d for 4 cols)
        for (int idx = tid; idx < 320; idx += 256) {
            int row = idx >> 4;
            int c4 = (idx & 15) << 2;
            int gi = row >> 2;
            int jj = j0 + (row & 3);
            const float* src;
            if (gi < 4) {
                src = (first_half ? W_hh : W_ih) +
                      (size_t)(gi * 1024 + jj) * 1024 + kc + c4;
            } else {
                if (!first_half) continue;  // stale data never read
                src = W_d + (size_t)jj * 1024 + kc + c4;
            }
            *(float4*)&ws[row][c4] = *(const float4*)src;
        }
        __syncthreads();

        const int kbase = rep << 4;  // 16-wide K slice per rep
#pragma unroll
        for (int kq = 0; kq < 16; kq += 4) {
            const int kk = kbase + kq;
            float4 wv[5];
#pragma unroll
            for (int g = 0; g < 5; ++g)
                wv[g] = *(const float4*)&ws[(g << 2) + jl][kk];
#pragma unroll
            for (int i = 0; i < 4; ++i) {
                const int b = bq + (i << 4);
                float4 hv = *(const float4*)&hs[b][kk];
#pragma unroll
                for (int g = 0; g < 4; ++g) {
                    acc[i][g] = fmaf(hv.x, wv[g].x, acc[i][g]);
                    acc[i][g] = fmaf(hv.y, wv[g].y, acc[i][g]);
                    acc[i][g] = fmaf(hv.z, wv[g].z, acc[i][g]);
                    acc[i][g] = fmaf(hv.w, wv[g].w, acc[i][g]);
                }
                if (first_half) {
                    float4 cv = *(const float4*)&cs[b][kk];
                    acc[i][4] = fmaf(cv.x, wv[4].x, acc[i][4]);
                    acc[i][4] = fmaf(cv.y, wv[4].y, acc[i][4]);
                    acc[i][4] = fmaf(cv.z, wv[4].z, acc[i][4]);
                    acc[i][4] = fmaf(cv.w, wv[4].w, acc[i][4]);
                }
            }
        }
        __syncthreads();
    }

    // cross-rep reduction
#pragma unroll
    for (int i = 0; i < 4; ++i)
#pragma unroll
        for (int g = 0; g < 5; ++g)
            red[tid][i * 5 + g] = acc[i][g];
    __syncthreads();

    if (tid < 64) {  // rep==0 threads finish
#pragma unroll
        for (int r = 1; r < 4; ++r)
#pragma unroll
            for (int i = 0; i < 4; ++i)
#pragma unroll
                for (int g = 0; g < 5; ++g)
                    acc[i][g] += red[tid + 64 * r][i * 5 + g];

#pragma unroll
        for (int i = 0; i < 4; ++i) {
            const int b = bq + (i << 4);
            float pre_i, pre_f, pre_g, pre_o;
            if (!FUSED) {
                const float* g = gvec + (size_t)b * G4 + j;
                pre_i = acc[i][0] + g[0];
                pre_f = acc[i][1] + g[1024];
                pre_g = acc[i][2] + g[2048];
                pre_o = acc[i][3] + g[3072];
            } else {
                pre_i = acc[i][0] + b_ih[j] + b_hh[j];
                pre_f = acc[i][1] + b_ih[H + j] + b_hh[H + j];
                pre_g = acc[i][2] + b_ih[2 * H + j] + b_hh[2 * H + j];
                pre_o = acc[i][3] + b_ih[3 * H + j] + b_hh[3 * H + j];
            }
            float Cs = tanhf(acc[i][4] + b_d[j]);
            float c_old = c_in[(size_t)b * H + j];
            float dec = 1.0f / logf(2.718281828459045235f + dts[b]);
            float c_star = (c_old - Cs) + Cs * dec;
            float si = sigmoidf_(pre_i);
            float sf = sigmoidf_(pre_f);
            float so = sigmoidf_(pre_o);
            float c_new = sf * c_star + si * tanhf(pre_g);
            float h_new = so * tanhf(c_new);
            c_out[(size_t)b * H + j] = c_new;
            h_out[(size_t)b * H + j] = h_new;
        }
    }
}

}  // namespace

extern "C" void kernel_launch(void* const* d_in, const int* in_sizes, int n_in,
                              void* d_out, int out_size, void* d_ws, size_t ws_size,
                              hipStream_t stream)
{
    const float* x    = (const float*)d_in[0];
    const float* h0   = (const float*)d_in[1];
    const float* c0   = (const float*)d_in[2];
    const float* dts  = (const float*)d_in[3];
    const float* W_ih = (const float*)d_in[4];
    const float* W_hh = (const float*)d_in[5];
    const float* b_ih = (const float*)d_in[6];
    const float* b_hh = (const float*)d_in[7];
    const float* W_d  = (const float*)d_in[8];
    const float* b_d  = (const float*)d_in[9];

    float* outs = (float*)d_out;
    const size_t BH = (size_t)B * H;
    float* h_sec = outs + (size_t)T * BH;   // final-h section of d_out
    float* c_sec = h_sec + BH;              // final-c section of d_out
    // Use the (unread-until-the-end) h/c output sections as the c ping-pong.
    float* cb[2] = { h_sec, c_sec };

    float* G = (float*)d_ws;
    const size_t g_bytes = (size_t)T * B * G4 * sizeof(float);
    const bool useG = (ws_size >= g_bytes);

    hipMemcpyAsync(cb[0], c0, BH * sizeof(float), hipMemcpyDeviceToDevice, stream);

    if (useG) {
        dim3 grid(G4 / 64, (T * B) / 64);
        gemm_xWih_kernel<<<grid, 256, 0, stream>>>(x, W_ih, b_ih, b_hh, G);
    }

    int p = 0;
    for (int t = T - 1; t >= 0; --t) {
        const float* h_in = (t == T - 1) ? h0 : outs + (size_t)(t + 1) * BH;
        const float* c_in = cb[p];
        float* c_out = cb[p ^ 1];
        float* h_out = outs + (size_t)t * BH;
        if (useG) {
            tlstm_step<false><<<256, 256, 0, stream>>>(
                h_in, c_in, G + (size_t)t * B * G4,
                W_hh, W_ih, W_d, b_ih, b_hh, b_d, dts, h_out, c_out);
        } else {
            tlstm_step<true><<<256, 256, 0, stream>>>(
                h_in, c_in, x + (size_t)t * B * D,
                W_hh, W_ih, W_d, b_ih, b_hh, b_d, dts, h_out, c_out);
        }
        p ^= 1;
    }

    // final c currently lives in cb[0] == h_sec; save it, then final h = outs[0]
    hipMemcpyAsync(c_sec, h_sec, BH * sizeof(float), hipMemcpyDeviceToDevice, stream);
    hipMemcpyAsync(h_sec, outs, BH * sizeof(float), hipMemcpyDeviceToDevice, stream);
}

// Round 6
// 13397.682 us; speedup vs baseline: 2.0198x; 2.0198x over previous
//
#include <hip/hip_runtime.h>
#include <math.h>

namespace {

typedef unsigned short ushort_t;
typedef unsigned int u32;
typedef __attribute__((ext_vector_type(8))) short bf16x8;   // MFMA A/B frag (4 VGPR)
typedef __attribute__((ext_vector_type(4))) float f32x4;    // MFMA C/D frag

constexpr int T = 512;
constexpr int B = 64;
constexpr int D = 1024;
constexpr int H = 1024;
constexpr int G4 = 4 * H;  // 4096

__device__ __forceinline__ ushort_t f2bf(float f) {
    u32 u = __float_as_uint(f);
    u32 r = (u + 0x7FFFu + ((u >> 16) & 1u)) >> 16;  // RNE
    return (ushort_t)r;
}
__device__ __forceinline__ float sigmoidf_(float v) {
    return 1.0f / (1.0f + expf(-v));
}
__device__ __forceinline__ bf16x8 ldg8(const ushort_t* p) {
    return *reinterpret_cast<const bf16x8*>(p);
}

// ---------------------------------------------------------------------------
// fp32 -> bf16 bulk conversion (8 elts/thread/iter, grid-stride)
// ---------------------------------------------------------------------------
__global__ __launch_bounds__(256)
void f32_to_bf16_kernel(const float* __restrict__ src, ushort_t* __restrict__ dst, int n8) {
    for (int i = blockIdx.x * blockDim.x + threadIdx.x; i < n8; i += gridDim.x * blockDim.x) {
        float4 a = *reinterpret_cast<const float4*>(src + (size_t)i * 8);
        float4 b = *reinterpret_cast<const float4*>(src + (size_t)i * 8 + 4);
        union { ushort_t u[8]; uint4 v; } r;
        r.u[0] = f2bf(a.x); r.u[1] = f2bf(a.y); r.u[2] = f2bf(a.z); r.u[3] = f2bf(a.w);
        r.u[4] = f2bf(b.x); r.u[5] = f2bf(b.y); r.u[6] = f2bf(b.z); r.u[7] = f2bf(b.w);
        *reinterpret_cast<uint4*>(dst + (size_t)i * 8) = r.v;
    }
}

// h0/c0 -> bf16 pings, c0 -> fp32 ping, bsum = b_ih + b_hh
__global__ __launch_bounds__(256)
void prep_state_kernel(const float* __restrict__ h0, const float* __restrict__ c0,
                       ushort_t* __restrict__ hb0, ushort_t* __restrict__ cb0,
                       float* __restrict__ cf0,
                       const float* __restrict__ b_ih, const float* __restrict__ b_hh,
                       float* __restrict__ bsum) {
    int i = blockIdx.x * 256 + threadIdx.x;  // grid 256 -> 65536 threads
    float h = h0[i], c = c0[i];
    hb0[i] = f2bf(h);
    cb0[i] = f2bf(c);
    cf0[i] = c;
    if (i < G4) bsum[i] = b_ih[i] + b_hh[i];
}

// ---------------------------------------------------------------------------
// Phase 1: G[m][n] = x_bf16[m]·W_ih_bf16[n] + bsum[n]   (M=32768, N=4096, K=1024)
// bf16 MFMA 16x16x32, 128x128 tile, BK=64, 4 waves (2x2), reg-staged LDS with
// XOR-swizzle (byte ^= (row&7)<<4) to kill the stride-128B bank conflict (G4/T2).
// ---------------------------------------------------------------------------
__global__ __launch_bounds__(256)
void gemm_G_kernel(const ushort_t* __restrict__ Ab,   // [32768][1024] bf16
                   const ushort_t* __restrict__ Bb,   // [4096][1024] bf16 (B^T layout)
                   const float* __restrict__ bsum,    // [4096]
                   float* __restrict__ G)             // [32768][4096] fp32
{
    __shared__ __align__(16) char AsB[128 * 64 * 2];
    __shared__ __align__(16) char BsB[128 * 64 * 2];

    const int tid  = threadIdx.x;
    const int m0   = blockIdx.y * 128;
    const int n0   = blockIdx.x * 128;   // grid.x fastest => m-stripe shares A slice in L2
    const int wave = tid >> 6;
    const int lane = tid & 63;
    const int wm = wave >> 1, wn = wave & 1;
    const int lr = lane & 15, hi = lane >> 4;

    f32x4 acc[4][4] = {};

#pragma unroll 1
    for (int k0 = 0; k0 < 1024; k0 += 64) {
        // stage A,B tiles: 128 rows x 8 granules(16B); swizzled granule = g ^ (r&7)
#pragma unroll
        for (int l = 0; l < 4; ++l) {
            int idx = l * 256 + tid;
            int r = idx >> 3, g = idx & 7;
            uint4 va = *reinterpret_cast<const uint4*>(Ab + (size_t)(m0 + r) * 1024 + k0 + g * 8);
            *reinterpret_cast<uint4*>(AsB + r * 128 + ((g ^ (r & 7)) << 4)) = va;
            uint4 vb = *reinterpret_cast<const uint4*>(Bb + (size_t)(n0 + r) * 1024 + k0 + g * 8);
            *reinterpret_cast<uint4*>(BsB + r * 128 + ((g ^ (r & 7)) << 4)) = vb;
        }
        __syncthreads();

#pragma unroll
        for (int ks = 0; ks < 2; ++ks) {
            bf16x8 af[4], bf[4];
#pragma unroll
            for (int i = 0; i < 4; ++i) {
                int row = wm * 64 + i * 16 + lr;
                int gr = (ks * 4 + hi) ^ (row & 7);
                af[i] = *reinterpret_cast<const bf16x8*>(AsB + row * 128 + (gr << 4));
            }
#pragma unroll
            for (int j = 0; j < 4; ++j) {
                int row = wn * 64 + j * 16 + lr;
                int gr = (ks * 4 + hi) ^ (row & 7);
                bf[j] = *reinterpret_cast<const bf16x8*>(BsB + row * 128 + (gr << 4));
            }
#pragma unroll
            for (int i = 0; i < 4; ++i)
#pragma unroll
                for (int j = 0; j < 4; ++j)
                    acc[i][j] = __builtin_amdgcn_mfma_f32_16x16x32_bf16(af[i], bf[j], acc[i][j], 0, 0, 0);
        }
        __syncthreads();
    }

    // D frag: row(M) = hi*4 + reg, col(N) = lr  [m89-verified]
#pragma unroll
    for (int i = 0; i < 4; ++i)
#pragma unroll
        for (int j = 0; j < 4; ++j) {
            int n = n0 + wn * 64 + j * 16 + lr;
            float bs = bsum[n];
#pragma unroll
            for (int r = 0; r < 4; ++r) {
                int m = m0 + wm * 64 + i * 16 + hi * 4 + r;
                G[(size_t)m * G4 + n] = acc[i][j][r] + bs;
            }
        }
}

// ---------------------------------------------------------------------------
// Phase 2 step: 256 blocks x 64 threads (1 wave). Block = (jb = bid&63 -> j-16
// slice) x (mh = bid>>6 -> 16-batch slice). Wave computes 5 MFMA families
// (i,f,g,o via W_hh; d via W_d) global-direct (no LDS): per kstep-32, 7 16B
// frag loads (L2-hot: weights 10.5MB bf16, h/c 128KB each) + 5 MFMAs.
// FUSED adds the x·W_ih gate contribution (second K=1024 loop).
// ---------------------------------------------------------------------------
template <bool FUSED>
__global__ __launch_bounds__(64)
void step_mfma_kernel(const ushort_t* __restrict__ hb,   // [64][1024] bf16
                      const ushort_t* __restrict__ cb,   // [64][1024] bf16
                      const float*    __restrict__ cf,   // [64][1024] fp32
                      const float*    __restrict__ gsrc, // !FUSED: G + t*B*4096
                      const ushort_t* __restrict__ xbt,  // FUSED: x_bf16 + t*B*D
                      const ushort_t* __restrict__ whb,  // [4096][1024] bf16
                      const ushort_t* __restrict__ wib,  // [4096][1024] bf16
                      const ushort_t* __restrict__ wdb,  // [1024][1024] bf16
                      const float* __restrict__ bsum,    // [4096] (FUSED)
                      const float* __restrict__ b_d,
                      const float* __restrict__ dts,
                      float* __restrict__ h_f32_out,     // outs + t*B*H
                      ushort_t* __restrict__ hb_out,
                      ushort_t* __restrict__ cb_out,
                      float* __restrict__ cf_out)
{
    const int lane = threadIdx.x;
    const int jb = blockIdx.x & 63;
    const int mh = blockIdx.x >> 6;
    const int j0 = jb * 16, b0 = mh * 16;
    const int lr = lane & 15, hi = lane >> 4;

    f32x4 acc0 = {}, acc1 = {}, acc2 = {}, acc3 = {}, acc4 = {};

    const ushort_t* hA = hb + (size_t)(b0 + lr) * 1024 + hi * 8;
    const ushort_t* cA = cb + (size_t)(b0 + lr) * 1024 + hi * 8;
    const ushort_t* w0 = whb + (size_t)(0 * 1024 + j0 + lr) * 1024 + hi * 8;
    const ushort_t* w1 = whb + (size_t)(1 * 1024 + j0 + lr) * 1024 + hi * 8;
    const ushort_t* w2 = whb + (size_t)(2 * 1024 + j0 + lr) * 1024 + hi * 8;
    const ushort_t* w3 = whb + (size_t)(3 * 1024 + j0 + lr) * 1024 + hi * 8;
    const ushort_t* w4 = wdb + (size_t)(j0 + lr) * 1024 + hi * 8;

#pragma unroll 2
    for (int k = 0; k < 1024; k += 32) {
        bf16x8 ah = ldg8(hA + k);
        bf16x8 ac = ldg8(cA + k);
        bf16x8 b0v = ldg8(w0 + k), b1v = ldg8(w1 + k), b2v = ldg8(w2 + k),
               b3v = ldg8(w3 + k), b4v = ldg8(w4 + k);
        acc0 = __builtin_amdgcn_mfma_f32_16x16x32_bf16(ah, b0v, acc0, 0, 0, 0);
        acc1 = __builtin_amdgcn_mfma_f32_16x16x32_bf16(ah, b1v, acc1, 0, 0, 0);
        acc2 = __builtin_amdgcn_mfma_f32_16x16x32_bf16(ah, b2v, acc2, 0, 0, 0);
        acc3 = __builtin_amdgcn_mfma_f32_16x16x32_bf16(ah, b3v, acc3, 0, 0, 0);
        acc4 = __builtin_amdgcn_mfma_f32_16x16x32_bf16(ac, b4v, acc4, 0, 0, 0);
    }

    if (FUSED) {
        const ushort_t* xA = xbt + (size_t)(b0 + lr) * 1024 + hi * 8;
        const ushort_t* v0 = wib + (size_t)(0 * 1024 + j0 + lr) * 1024 + hi * 8;
        const ushort_t* v1 = wib + (size_t)(1 * 1024 + j0 + lr) * 1024 + hi * 8;
        const ushort_t* v2 = wib + (size_t)(2 * 1024 + j0 + lr) * 1024 + hi * 8;
        const ushort_t* v3 = wib + (size_t)(3 * 1024 + j0 + lr) * 1024 + hi * 8;
#pragma unroll 2
        for (int k = 0; k < 1024; k += 32) {
            bf16x8 ax = ldg8(xA + k);
            bf16x8 b0v = ldg8(v0 + k), b1v = ldg8(v1 + k), b2v = ldg8(v2 + k), b3v = ldg8(v3 + k);
            acc0 = __builtin_amdgcn_mfma_f32_16x16x32_bf16(ax, b0v, acc0, 0, 0, 0);
            acc1 = __builtin_amdgcn_mfma_f32_16x16x32_bf16(ax, b1v, acc1, 0, 0, 0);
            acc2 = __builtin_amdgcn_mfma_f32_16x16x32_bf16(ax, b2v, acc2, 0, 0, 0);
            acc3 = __builtin_amdgcn_mfma_f32_16x16x32_bf16(ax, b3v, acc3, 0, 0, 0);
        }
    }

    // epilogue: lane holds (b = b0 + hi*4 + r, j = j0 + lr) for r=0..3
    const int j = j0 + lr;
    const float bd = b_d[j];
    float bs0 = 0.f, bs1 = 0.f, bs2 = 0.f, bs3 = 0.f;
    if (FUSED) {
        bs0 = bsum[j]; bs1 = bsum[H + j]; bs2 = bsum[2 * H + j]; bs3 = bsum[3 * H + j];
    }
#pragma unroll
    for (int r = 0; r < 4; ++r) {
        const int b = b0 + hi * 4 + r;
        float pi, pf, pg, po;
        if (!FUSED) {
            const float* g = gsrc + (size_t)b * G4 + j;
            pi = acc0[r] + g[0];
            pf = acc1[r] + g[1024];
            pg = acc2[r] + g[2048];
            po = acc3[r] + g[3072];
        } else {
            pi = acc0[r] + bs0; pf = acc1[r] + bs1;
            pg = acc2[r] + bs2; po = acc3[r] + bs3;
        }
        float Cs = tanhf(acc4[r] + bd);
        size_t o = (size_t)b * H + j;
        float c_old = cf[o];
        float dec = 1.0f / logf(2.718281828459045235f + dts[b]);
        float c_star = (c_old - Cs) + Cs * dec;
        float cn = sigmoidf_(pf) * c_star + sigmoidf_(pi) * tanhf(pg);
        float hn = sigmoidf_(po) * tanhf(cn);
        h_f32_out[o] = hn;
        hb_out[o] = f2bf(hn);
        cb_out[o] = f2bf(cn);
        cf_out[o] = cn;
    }
}

// ---------------------------------------------------------------------------
// Tier C legacy (tiny ws): round-0 fp32 fused step, d_out-section ping-pong.
// ---------------------------------------------------------------------------
__global__ __launch_bounds__(256)
void tlstm_step_legacy(const float* __restrict__ h_in, const float* __restrict__ c_in,
                       const float* __restrict__ x_t,
                       const float* __restrict__ W_hh, const float* __restrict__ W_ih,
                       const float* __restrict__ W_d,
                       const float* __restrict__ b_ih, const float* __restrict__ b_hh,
                       const float* __restrict__ b_d, const float* __restrict__ dts,
                       float* __restrict__ h_out, float* __restrict__ c_out)
{
    __shared__ float hs[64][68];
    __shared__ float cs[64][68];
    __shared__ float ws[20][68];
    __shared__ float red[256][21];

    const int tid = threadIdx.x;
    const int j0 = blockIdx.x * 4;
    const int bq = tid & 15;
    const int jl = (tid >> 4) & 3;
    const int rep = tid >> 6;
    const int j = j0 + jl;

    float acc[4][5] = {};

#pragma unroll 1
    for (int k0 = 0; k0 < 2048; k0 += 64) {
        const bool first_half = (k0 < 1024);
        const int kc = first_half ? k0 : (k0 - 1024);
        const float* hsrc = first_half ? h_in : x_t;
#pragma unroll
        for (int l = 0; l < 4; ++l) {
            int idx = l * 256 + tid;
            int r = idx >> 4;
            int c4 = (idx & 15) << 2;
            *(float4*)&hs[r][c4] = *(const float4*)(hsrc + (size_t)r * 1024 + kc + c4);
        }
        if (first_half) {
#pragma unroll
            for (int l = 0; l < 4; ++l) {
                int idx = l * 256 + tid;
                int r = idx >> 4;
                int c4 = (idx & 15) << 2;
                *(float4*)&cs[r][c4] = *(const float4*)(c_in + (size_t)r * 1024 + kc + c4);
            }
        }
        for (int idx = tid; idx < 320; idx += 256) {
            int row = idx >> 4;
            int c4 = (idx & 15) << 2;
            int gi = row >> 2;
            int jj = j0 + (row & 3);
            const float* src;
            if (gi < 4) {
                src = (first_half ? W_hh : W_ih) + (size_t)(gi * 1024 + jj) * 1024 + kc + c4;
            } else {
                if (!first_half) continue;
                src = W_d + (size_t)jj * 1024 + kc + c4;
            }
            *(float4*)&ws[row][c4] = *(const float4*)src;
        }
        __syncthreads();

        const int kbase = rep << 4;
#pragma unroll
        for (int kq = 0; kq < 16; kq += 4) {
            const int kk = kbase + kq;
            float4 wv[5];
#pragma unroll
            for (int g = 0; g < 5; ++g) wv[g] = *(const float4*)&ws[(g << 2) + jl][kk];
#pragma unroll
            for (int i = 0; i < 4; ++i) {
                const int b = bq + (i << 4);
                float4 hv = *(const float4*)&hs[b][kk];
#pragma unroll
                for (int g = 0; g < 4; ++g) {
                    acc[i][g] = fmaf(hv.x, wv[g].x, acc[i][g]);
                    acc[i][g] = fmaf(hv.y, wv[g].y, acc[i][g]);
                    acc[i][g] = fmaf(hv.z, wv[g].z, acc[i][g]);
                    acc[i][g] = fmaf(hv.w, wv[g].w, acc[i][g]);
                }
                if (first_half) {
                    float4 cv = *(const float4*)&cs[b][kk];
                    acc[i][4] = fmaf(cv.x, wv[4].x, acc[i][4]);
                    acc[i][4] = fmaf(cv.y, wv[4].y, acc[i][4]);
                    acc[i][4] = fmaf(cv.z, wv[4].z, acc[i][4]);
                    acc[i][4] = fmaf(cv.w, wv[4].w, acc[i][4]);
                }
            }
        }
        __syncthreads();
    }

#pragma unroll
    for (int i = 0; i < 4; ++i)
#pragma unroll
        for (int g = 0; g < 5; ++g) red[tid][i * 5 + g] = acc[i][g];
    __syncthreads();

    if (tid < 64) {
#pragma unroll
        for (int r = 1; r < 4; ++r)
#pragma unroll
            for (int i = 0; i < 4; ++i)
#pragma unroll
                for (int g = 0; g < 5; ++g) acc[i][g] += red[tid + 64 * r][i * 5 + g];
#pragma unroll
        for (int i = 0; i < 4; ++i) {
            const int b = bq + (i << 4);
            float pi = acc[i][0] + b_ih[j] + b_hh[j];
            float pf = acc[i][1] + b_ih[H + j] + b_hh[H + j];
            float pg = acc[i][2] + b_ih[2 * H + j] + b_hh[2 * H + j];
            float po = acc[i][3] + b_ih[3 * H + j] + b_hh[3 * H + j];
            float Cs = tanhf(acc[i][4] + b_d[j]);
            float c_old = c_in[(size_t)b * H + j];
            float dec = 1.0f / logf(2.718281828459045235f + dts[b]);
            float c_star = (c_old - Cs) + Cs * dec;
            float cn = sigmoidf_(pf) * c_star + sigmoidf_(pi) * tanhf(pg);
            float hn = sigmoidf_(po) * tanhf(cn);
            c_out[(size_t)b * H + j] = cn;
            h_out[(size_t)b * H + j] = hn;
        }
    }
}

}  // namespace

extern "C" void kernel_launch(void* const* d_in, const int* in_sizes, int n_in,
                              void* d_out, int out_size, void* d_ws, size_t ws_size,
                              hipStream_t stream)
{
    const float* x    = (const float*)d_in[0];
    const float* h0   = (const float*)d_in[1];
    const float* c0   = (const float*)d_in[2];
    const float* dts  = (const float*)d_in[3];
    const float* W_ih = (const float*)d_in[4];
    const float* W_hh = (const float*)d_in[5];
    const float* b_ih = (const float*)d_in[6];
    const float* b_hh = (const float*)d_in[7];
    const float* W_d  = (const float*)d_in[8];
    const float* b_d  = (const float*)d_in[9];

    float* outs = (float*)d_out;
    const size_t BH = (size_t)B * H;
    float* h_sec = outs + (size_t)T * BH;
    float* c_sec = h_sec + BH;

    // ws layout
    char* wsb = (char*)d_ws;
    size_t off = 0;
    auto take = [&](size_t n) { size_t o = off; off += (n + 255) & ~(size_t)255; return o; };
    size_t o_xb  = take((size_t)T * B * D * 2);
    size_t o_wib = take((size_t)G4 * D * 2);
    size_t o_whb = take((size_t)G4 * H * 2);
    size_t o_wdb = take((size_t)H * H * 2);
    size_t o_bs  = take((size_t)G4 * 4);
    size_t o_hb0 = take(BH * 2), o_hb1 = take(BH * 2);
    size_t o_cb0 = take(BH * 2), o_cb1 = take(BH * 2);
    size_t o_cf0 = take(BH * 4), o_cf1 = take(BH * 4);
    size_t needB = off;
    size_t o_G = take((size_t)T * B * G4 * 4);
    size_t needA = off;

    const bool tierB = ws_size >= needB;
    const bool tierA = ws_size >= needA;

    if (!tierB) {
        // ---- Tier C: legacy fp32 path (no ws needed) ----
        float* cbp[2] = { h_sec, c_sec };
        hipMemcpyAsync(cbp[0], c0, BH * sizeof(float), hipMemcpyDeviceToDevice, stream);
        int p = 0;
        for (int t = T - 1; t >= 0; --t) {
            const float* h_in = (t == T - 1) ? h0 : outs + (size_t)(t + 1) * BH;
            tlstm_step_legacy<<<256, 256, 0, stream>>>(
                h_in, cbp[p], x + (size_t)t * B * D,
                W_hh, W_ih, W_d, b_ih, b_hh, b_d, dts,
                outs + (size_t)t * BH, cbp[p ^ 1]);
            p ^= 1;
        }
        hipMemcpyAsync(c_sec, h_sec, BH * sizeof(float), hipMemcpyDeviceToDevice, stream);
        hipMemcpyAsync(h_sec, outs, BH * sizeof(float), hipMemcpyDeviceToDevice, stream);
        return;
    }

    ushort_t* xb  = (ushort_t*)(wsb + o_xb);
    ushort_t* wib = (ushort_t*)(wsb + o_wib);
    ushort_t* whb = (ushort_t*)(wsb + o_whb);
    ushort_t* wdb = (ushort_t*)(wsb + o_wdb);
    float*    bsum = (float*)(wsb + o_bs);
    ushort_t* hbp[2] = { (ushort_t*)(wsb + o_hb0), (ushort_t*)(wsb + o_hb1) };
    ushort_t* cbp[2] = { (ushort_t*)(wsb + o_cb0), (ushort_t*)(wsb + o_cb1) };
    float*    cfp[2] = { (float*)(wsb + o_cf0), (float*)(wsb + o_cf1) };
    float*    G = (float*)(wsb + o_G);

    // conversions
    {
        int n8;
        n8 = T * B * D / 8;
        f32_to_bf16_kernel<<<2048, 256, 0, stream>>>(x, xb, n8);
        n8 = G4 * D / 8;
        f32_to_bf16_kernel<<<2048, 256, 0, stream>>>(W_ih, wib, n8);
        n8 = G4 * H / 8;
        f32_to_bf16_kernel<<<2048, 256, 0, stream>>>(W_hh, whb, n8);
        n8 = H * H / 8;
        f32_to_bf16_kernel<<<512, 256, 0, stream>>>(W_d, wdb, n8);
        prep_state_kernel<<<256, 256, 0, stream>>>(h0, c0, hbp[0], cbp[0], cfp[0], b_ih, b_hh, bsum);
    }

    if (tierA) {
        gemm_G_kernel<<<dim3(G4 / 128, (T * B) / 128), 256, 0, stream>>>(xb, wib, bsum, G);
    }

    int p = 0;
    for (int t = T - 1; t >= 0; --t) {
        float* h_out = outs + (size_t)t * BH;
        if (tierA) {
            step_mfma_kernel<false><<<256, 64, 0, stream>>>(
                hbp[p], cbp[p], cfp[p], G + (size_t)t * B * G4, nullptr,
                whb, wib, wdb, bsum, b_d, dts,
                h_out, hbp[p ^ 1], cbp[p ^ 1], cfp[p ^ 1]);
        } else {
            step_mfma_kernel<true><<<256, 64, 0, stream>>>(
                hbp[p], cbp[p], cfp[p], nullptr, xb + (size_t)t * B * D,
                whb, wib, wdb, bsum, b_d, dts,
                h_out, hbp[p ^ 1], cbp[p ^ 1], cfp[p ^ 1]);
        }
        p ^= 1;
    }

    // after 512 steps (even), final state sits in index-0 buffers
    hipMemcpyAsync(c_sec, cfp[0], BH * sizeof(float), hipMemcpyDeviceToDevice, stream);
    hipMemcpyAsync(h_sec, outs, BH * sizeof(float), hipMemcpyDeviceToDevice, stream);
}